// Round 9
// baseline (38.638 us; speedup 1.0000x reference)
//
#include <hip/hip_runtime.h>

// ROI Align forward, fp32. Fixed shapes:
//   input: (N=4, C=256, H=200, W=200) f32   (164 MB)
//   rois:  (M=1024, 5) f32   [batch_idx, x1, y1, x2, y2]
//   out:   (M, C, 7, 7) f32                 (51 MB)
//
// Fused single-kernel, L2-locality-scheduled, dense-lane design:
//   - grid = 8 XCDs x 8 c-groups x 64 roi-groups; XCD = blockIdx%8 owns a
//     32-channel slice; roi-group varies fastest so concurrent blocks on an
//     XCD share a ~2.5 MB input window (fits 4 MB XCD-L2).
//   - per-block table (16 ROIs x 49 positions) built in-kernel into LDS.
//   - gather: each wave owns 4 ROIs x 4 channels x 49 positions = 784 items,
//     iterated as 13 x 64-lane dense steps (item = (roi,c,pos) flattened,
//     c*49+pos matches output layout -> contiguous 64-lane stores).
//     Lane waste 23% -> 6%; fewer, denser memory instructions.

#define OUT_H 7
#define OUT_W 7
#define NPOS 49
#define SPATIAL_SCALE 0.25f
#define C_CONST 256
#define H_CONST 200
#define W_CONST 200
#define HW_CONST (H_CONST * W_CONST)
#define M_CONST 1024
#define CPB 4                    // channels per block
#define RPB 16                   // ROIs per block
#define WAVE_ITEMS (4 * CPB * NPOS)   // 784 items per wave
#define WAVE_ITERS ((WAVE_ITEMS + 63) / 64)   // 13

__device__ __forceinline__ void roi_entry(const float* __restrict__ r,
                                          int pos, int2& off, float4& w) {
    const int ph = pos / OUT_W;
    const int pw = pos - ph * OUT_W;

    const int   b  = (int)r[0];
    const float x1 = r[1] * SPATIAL_SCALE;
    const float y1 = r[2] * SPATIAL_SCALE;
    const float x2 = r[3] * SPATIAL_SCALE;
    const float y2 = r[4] * SPATIAL_SCALE;

    const float roi_w = fmaxf(x2 - x1, 1.0f);
    const float roi_h = fmaxf(y2 - y1, 1.0f);
    const float bin_w = roi_w * (1.0f / OUT_W);
    const float bin_h = roi_h * (1.0f / OUT_H);

    const float y_s = y1 + ((float)ph + 0.5f) * bin_h;
    const float x_s = x1 + ((float)pw + 0.5f) * bin_w;
    const float py  = y_s * ((float)(H_CONST - 1) / (float)H_CONST);
    const float px  = x_s * ((float)(W_CONST - 1) / (float)W_CONST);

    const float fy = floorf(py);
    const float fx = floorf(px);
    const int y0 = (int)fy;
    const int x0 = (int)fx;
    const float ly = py - fy;
    const float lx = px - fx;

    const int y1i = y0 + 1;
    const int x1i = x0 + 1;

    const bool vy0 = (y0  >= 0) & (y0  < H_CONST);
    const bool vy1 = (y1i >= 0) & (y1i < H_CONST);
    const bool vx0 = (x0  >= 0) & (x0  < W_CONST);
    const bool vx1 = (x1i >= 0) & (x1i < W_CONST);

    const int y0c = min(max(y0,  0), H_CONST - 1);
    const int y1c = min(max(y1i, 0), H_CONST - 1);
    const int x0c = min(max(x0,  0), W_CONST - 1);
    const int x1c = min(max(x1i, 0), W_CONST - 1);

    float w00 = (1.0f - ly) * (1.0f - lx);
    float w01 = (1.0f - ly) * lx;
    float w10 = ly * (1.0f - lx);
    float w11 = ly * lx;
    w00 = (vy0 & vx0) ? w00 : 0.0f;
    w01 = (vy0 & vx1) ? w01 : 0.0f;
    w10 = (vy1 & vx0) ? w10 : 0.0f;
    w11 = (vy1 & vx1) ? w11 : 0.0f;

    // pair start + selection folding (x0c, x1c always ∈ {xs, xs+1})
    const int xs   = min(max(x0, 0), W_CONST - 2);
    const int sel0 = x0c - xs;
    const int sel1 = x1c - xs;
    const float WT0 = (sel0 == 0 ? w00 : 0.0f) + (sel1 == 0 ? w01 : 0.0f);
    const float WT1 = (sel0 == 1 ? w00 : 0.0f) + (sel1 == 1 ? w01 : 0.0f);
    const float WB0 = (sel0 == 0 ? w10 : 0.0f) + (sel1 == 0 ? w11 : 0.0f);
    const float WB1 = (sel0 == 1 ? w10 : 0.0f) + (sel1 == 1 ? w11 : 0.0f);

    const int nb = b * (C_CONST * HW_CONST);
    off = make_int2(nb + y0c * W_CONST + xs,
                    nb + y1c * W_CONST + xs);
    w   = make_float4(WT0, WT1, WB0, WB1);
}

// grid = 8 XCDs x 8 c-groups x 64 roi-groups = 4096 blocks.
__global__ __launch_bounds__(256) void roi_align_fused(
        const float* __restrict__ inp,
        const float* __restrict__ rois,
        float* __restrict__ out) {
    const int B   = blockIdx.x;
    const int xcd = B & 7;
    const int s   = B >> 3;            // 0..511
    const int cg  = s >> 6;            // 0..7  (slow)
    const int rg  = s & 63;            // 0..63 (fast)
    const int c0  = (xcd * 8 + cg) * CPB;   // XCD owns channels [xcd*32, xcd*32+32)
    const int m0  = rg * RPB;

    __shared__ int2   s_off[RPB * NPOS];   // 6.3 KB
    __shared__ float4 s_w[RPB * NPOS];     // 12.5 KB

    // ---- in-kernel table build: 784 entries over 256 threads ----
    for (int e = threadIdx.x; e < RPB * NPOS; e += 256) {
        const int mloc = e / NPOS;
        const int pos  = e - mloc * NPOS;
        int2 off; float4 w;
        roi_entry(rois + (size_t)(m0 + mloc) * 5, pos, off, w);
        s_off[e] = off;
        s_w[e]   = w;
    }
    __syncthreads();

    const int lane = threadIdx.x & 63;
    const int wid  = threadIdx.x >> 6;      // 0..3; wave owns 4 ROIs
    const int mbase = m0 + wid * 4;

    // Dense-lane gather: 784 items = (roi_local i, c, pos) flattened,
    // rem = c*NPOS+pos matches (c,pos) output layout -> contiguous stores.
    // Output base for item: ((mbase+i)*C + c0)*NPOS + rem.
    const size_t ob = ((size_t)mbase * C_CONST + c0) * NPOS;

#pragma unroll
    for (int it = 0; it < WAVE_ITERS; ++it) {
        const int g = it * 64 + lane;
        if (g < WAVE_ITEMS) {
            const unsigned i   = (unsigned)g / (CPB * NPOS);        // /196
            const unsigned rem = (unsigned)g - i * (CPB * NPOS);
            const unsigned c   = rem / NPOS;                        // /49
            const unsigned pos = rem - c * NPOS;

            const int t = (wid * 4 + (int)i) * NPOS + (int)pos;
            const int2   off = s_off[t];
            const float4 w   = s_w[t];

            const int e = (c0 + (int)c) * HW_CONST;
            float2 vT, vB;
            __builtin_memcpy(&vT, inp + (size_t)(unsigned)(off.x + e), 8);
            __builtin_memcpy(&vB, inp + (size_t)(unsigned)(off.y + e), 8);

            out[ob + (size_t)i * (C_CONST * NPOS) + rem] =
                w.x * vT.x + w.y * vT.y + w.z * vB.x + w.w * vB.y;
        }
    }
}

// Fallback for unexpected M: position-resident single kernel (round-4 style).
__global__ __launch_bounds__(256) void roi_align_fallback(
        const float* __restrict__ inp,
        const float* __restrict__ rois,
        float* __restrict__ out) {
    const int m   = blockIdx.x >> 1;
    const int seg = blockIdx.x & 1;

    __shared__ int2   s_off[NPOS];
    __shared__ float4 s_w[NPOS];

    const float* __restrict__ r = rois + (size_t)m * 5;

    if (threadIdx.x < NPOS) {
        int2 off; float4 w;
        roi_entry(r, threadIdx.x, off, w);
        s_off[threadIdx.x] = off;
        s_w[threadIdx.x]   = w;
    }
    __syncthreads();

    const int lane = threadIdx.x & 63;
    const int wid  = threadIdx.x >> 6;
    if (lane < NPOS) {
        const int2   off = s_off[lane];
        const float4 w   = s_w[lane];
        const int c0 = seg * (C_CONST / 2) + wid;
        const float* pT = inp + (size_t)(unsigned)(off.x + c0 * HW_CONST);
        const float* pB = inp + (size_t)(unsigned)(off.y + c0 * HW_CONST);
        float* po = out + (size_t)m * (C_CONST * NPOS) + (size_t)c0 * NPOS + lane;
        const int cstep = 4 * HW_CONST;
#pragma unroll 8
        for (int k = 0; k < C_CONST / 2 / 4; ++k) {
            float2 vT, vB;
            __builtin_memcpy(&vT, pT, 8);
            __builtin_memcpy(&vB, pB, 8);
            *po = w.x * vT.x + w.y * vT.y + w.z * vB.x + w.w * vB.y;
            pT += cstep; pB += cstep;
            po += 4 * NPOS;
        }
    }
}

extern "C" void kernel_launch(void* const* d_in, const int* in_sizes, int n_in,
                              void* d_out, int out_size, void* d_ws, size_t ws_size,
                              hipStream_t stream) {
    const float* inp  = (const float*)d_in[0];
    const float* rois = (const float*)d_in[1];
    float* out = (float*)d_out;

    const int M = in_sizes[1] / 5;

    if (M == M_CONST) {
        const int grid = 8 * 8 * 64;          // 4096 blocks
        roi_align_fused<<<grid, 256, 0, stream>>>(inp, rois, out);
    } else {
        roi_align_fallback<<<M * 2, 256, 0, stream>>>(inp, rois, out);
    }
}